// Round 1
// baseline (148.806 us; speedup 1.0000x reference)
//
#include <hip/hip_runtime.h>
#include <math.h>

// ---------------------------------------------------------------------------
// SelectiveAttention, bf16-MFMA, 3-kernel pipeline.
// R10 = R7/R9 base with band_attn_out restructured:
//   * phase 1 split: 1a = QK^T -> masked score strip in SHARED LDS (Ss),
//                    1b = PV with one d-tile per wave over all 320 keys.
//     This removes the old phase-2 cross-wave reduce (32 KB LDS round-trip
//     + reduce pass), cuts critical-wave PV MFMAs 12->10 (balanced), and
//     shrinks the PV accumulator 16->4 VGPRs. Barrier count unchanged (4).
//   * epilogue operand swap: A=WoT rows, B=att strip (same loads, swapped
//     MFMA args) -> D[m=out_col][n=q]; each lane holds 4 consecutive output
//     columns -> float4 stores (8 per wave vs 32 scalar) + float4 bias loads.
// prep_weights / proj_in are IDENTICAL to R9 (measured-best, untouched).
//
// B=4, S=4096, D=512, Dk=64, band=128.
// Accounting at 144.4 us: ~100 us harness fill/restore (fixed) + ~44 us
// kernels vs ~31 us floor. This round targets band_attn schedule fat only.
//
// MFMA 16x16x32 bf16 layouts (m89-verified):
//   A-frag: lane l holds A[m=l&15][k=(l>>4)*8+j]  (16B contiguous)
//   B-frag: lane l holds B[k=(l>>4)*8+j][n=l&15]  (B^T storage -> 16B reads)
//   C/D:    lane l, reg r -> C[row=(l>>4)*4+r][col=l&15]
// ---------------------------------------------------------------------------

typedef __bf16 bf16;
using bf16x4  = __attribute__((ext_vector_type(4))) __bf16;
using bf16x8  = __attribute__((ext_vector_type(8))) __bf16;
using floatx4 = __attribute__((ext_vector_type(4))) float;

#define MFMA(a, b, c) __builtin_amdgcn_mfma_f32_16x16x32_bf16(a, b, c, 0, 0, 0)

// WiT[n][k]=Wi[k][n] (64x512 bf16), WoT[n][k]=Wo[k][n] (512x64 bf16).
__global__ __launch_bounds__(256) void prep_weights(
    const float* __restrict__ Wi, const float* __restrict__ Wo,
    bf16* __restrict__ WiT, bf16* __restrict__ WoT)
{
    __shared__ float T[64][65];
    const int blk = blockIdx.x, tid = threadIdx.x;
    if (blk < 8) {
        const int k0 = blk * 64;
        #pragma unroll
        for (int i = 0; i < 4; i++) {
            int idx4 = tid * 4 + i;
            int r = idx4 >> 4, c4 = (idx4 & 15) * 4;
            float4 f = *(const float4*)(Wi + (size_t)(k0 + r) * 64 + c4);
            T[r][c4 + 0] = f.x; T[r][c4 + 1] = f.y;
            T[r][c4 + 2] = f.z; T[r][c4 + 3] = f.w;
        }
        __syncthreads();
        #pragma unroll
        for (int i = 0; i < 2; i++) {
            int seg = tid * 2 + i;
            int n = seg >> 3, k8 = (seg & 7) * 8;
            bf16x8 v;
            #pragma unroll
            for (int j = 0; j < 8; j++) v[j] = (bf16)T[k8 + j][n];
            *(bf16x8*)(WiT + (size_t)n * 512 + k0 + k8) = v;
        }
    } else {
        const int n0 = (blk - 8) * 64;
        #pragma unroll
        for (int i = 0; i < 4; i++) {
            int idx4 = tid * 4 + i;
            int r = idx4 >> 4, c4 = (idx4 & 15) * 4;
            float4 f = *(const float4*)(Wo + (size_t)r * 512 + n0 + c4);
            T[r][c4 + 0] = f.x; T[r][c4 + 1] = f.y;
            T[r][c4 + 2] = f.z; T[r][c4 + 3] = f.w;
        }
        __syncthreads();
        #pragma unroll
        for (int i = 0; i < 2; i++) {
            int seg = tid * 2 + i;
            int n = seg >> 3, k8 = (seg & 7) * 8;
            bf16x8 v;
            #pragma unroll
            for (int j = 0; j < 8; j++) v[j] = (bf16)T[k8 + j][n];
            *(bf16x8*)(WoT + (size_t)(n0 + n) * 64 + k8) = v;
        }
    }
}

// One block = 16 rows of value. Wave w covers k in [w*128,(w+1)*128). LDS
// reduce -> kvp row-major + kvT[d][s] transposed.  (UNCHANGED from R9.)
__global__ __launch_bounds__(256, 4) void proj_in_kernel(
    const float* __restrict__ v, const bf16* __restrict__ WiT,
    const float* __restrict__ bi, bf16* __restrict__ kvp,
    bf16* __restrict__ kvT, int K, int S)
{
    __shared__ float P[4][16][68];                    // [wave][row][col]
    const int tid = threadIdx.x;
    const int wave = tid >> 6, lane = tid & 63;
    const int lr = lane & 15, lq = lane >> 4;
    const int row0 = blockIdx.x * 16;
    const float* xrow = v + (size_t)(row0 + lr) * K + wave * 128;
    const bf16* wrow = WiT + wave * 128;

    floatx4 acc[4] = {};
    #pragma unroll
    for (int ks = 0; ks < 4; ks++) {
        const int k0 = ks * 32 + lq * 8;
        float4 a0 = *(const float4*)(xrow + k0);
        float4 a1 = *(const float4*)(xrow + k0 + 4);
        bf16x8 af;
        af[0] = (bf16)a0.x; af[1] = (bf16)a0.y; af[2] = (bf16)a0.z; af[3] = (bf16)a0.w;
        af[4] = (bf16)a1.x; af[5] = (bf16)a1.y; af[6] = (bf16)a1.z; af[7] = (bf16)a1.w;
        #pragma unroll
        for (int t = 0; t < 4; t++) {
            bf16x8 bfv = *(const bf16x8*)(wrow + (size_t)(t * 16 + lr) * K + k0);
            acc[t] = MFMA(af, bfv, acc[t]);
        }
    }
    #pragma unroll
    for (int t = 0; t < 4; t++)
        #pragma unroll
        for (int r = 0; r < 4; r++)
            P[wave][lq * 4 + r][t * 16 + lr] = acc[t][r];
    __syncthreads();

    {   // reduce + row-major write
        const int row = tid >> 4, c4 = (tid & 15) * 4;
        float4 s0 = *(const float4*)&P[0][row][c4];
        float4 s1 = *(const float4*)&P[1][row][c4];
        float4 s2 = *(const float4*)&P[2][row][c4];
        float4 s3 = *(const float4*)&P[3][row][c4];
        float4 bb = *(const float4*)(bi + c4);
        bf16x4 o;
        o[0] = (bf16)(s0.x + s1.x + s2.x + s3.x + bb.x);
        o[1] = (bf16)(s0.y + s1.y + s2.y + s3.y + bb.y);
        o[2] = (bf16)(s0.z + s1.z + s2.z + s3.z + bb.z);
        o[3] = (bf16)(s0.w + s1.w + s2.w + s3.w + bb.w);
        *(bf16x4*)(kvp + (size_t)(row0 + row) * 64 + c4) = o;
    }
    {   // kvT[d][s] transpose write
        const int d = tid >> 2, s4 = (tid & 3) * 4;
        const int b = row0 >> 12, s0r = row0 & (S - 1);
        const float bb = bi[d];
        bf16x4 o;
        #pragma unroll
        for (int i = 0; i < 4; i++) {
            float s = P[0][s4 + i][d] + P[1][s4 + i][d]
                    + P[2][s4 + i][d] + P[3][s4 + i][d] + bb;
            o[i] = (bf16)s;
        }
        *(bf16x4*)(kvT + ((size_t)b * 64 + d) * S + s0r + s4) = o;
    }
}

// One block = one 16-query strip; 4 waves cooperate.
// Phase 0: fused q-proj of own strip (K-split x4, LDS reduce, +bi, *scale).
// Phase 1a: QK^T over 10 half-chunks split {3,3,2,2} -> masked bf16 score
//           strip Ss[16 q][320 keys] (shared, cols relative to chunk base).
// Phase 1b: PV, one 16-wide d-tile per wave, all 10 chunks, acc in 4 VGPRs;
//           write own St columns directly (no cross-wave reduce needed).
// Phase 3: epilogue with swapped operands: D[m=out_col][n=q] -> each lane
//          stores 4 consecutive output columns as one float4.
__global__ __launch_bounds__(256, 4) void band_attn_out_kernel(
    const float* __restrict__ query, const bf16* __restrict__ WiT,
    const float* __restrict__ bi, const bf16* __restrict__ kvp,
    const bf16* __restrict__ kvT, const int* __restrict__ band_ptr,
    const bf16* __restrict__ WoT, const float* __restrict__ bo,
    float* __restrict__ out, int K, int S, float scale)
{
    __shared__ float P[4][16][68];                    // q-proj partials
    __shared__ bf16 Ss[16][344];                      // shared 320-key S strip
    __shared__ bf16 St[16][88];                       // q strip / att strip
    const int tid = threadIdx.x;
    const int wave = tid >> 6, lane = tid & 63;
    const int lr = lane & 15, lq = lane >> 4;
    const int gs = blockIdx.x;                        // strip id
    const int b = gs >> 8;                            // 256 strips per batch
    const int q0 = (gs & 255) * 16;
    const int band = band_ptr[0];

    // ---- phase 0: q-proj of rows [b*S+q0, +16) ----
    {
        const float* xrow = query + ((size_t)b * S + q0 + lr) * K + wave * 128;
        const bf16* wrow = WiT + wave * 128;
        floatx4 qa[4] = {};
        #pragma unroll
        for (int ks = 0; ks < 4; ks++) {
            const int k0 = ks * 32 + lq * 8;
            float4 a0 = *(const float4*)(xrow + k0);
            float4 a1 = *(const float4*)(xrow + k0 + 4);
            bf16x8 af;
            af[0] = (bf16)a0.x; af[1] = (bf16)a0.y; af[2] = (bf16)a0.z; af[3] = (bf16)a0.w;
            af[4] = (bf16)a1.x; af[5] = (bf16)a1.y; af[6] = (bf16)a1.z; af[7] = (bf16)a1.w;
            #pragma unroll
            for (int t = 0; t < 4; t++) {
                bf16x8 bfv = *(const bf16x8*)(wrow + (size_t)(t * 16 + lr) * K + k0);
                qa[t] = MFMA(af, bfv, qa[t]);
            }
        }
        #pragma unroll
        for (int t = 0; t < 4; t++)
            #pragma unroll
            for (int r = 0; r < 4; r++)
                P[wave][lq * 4 + r][t * 16 + lr] = qa[t][r];
    }
    __syncthreads();
    {   // reduce + bias + scale -> bf16 q strip
        const int row = tid >> 4, c4 = (tid & 15) * 4;
        float4 s0 = *(const float4*)&P[0][row][c4];
        float4 s1 = *(const float4*)&P[1][row][c4];
        float4 s2 = *(const float4*)&P[2][row][c4];
        float4 s3 = *(const float4*)&P[3][row][c4];
        float4 bb = *(const float4*)(bi + c4);
        bf16x4 o;
        o[0] = (bf16)((s0.x + s1.x + s2.x + s3.x + bb.x) * scale);
        o[1] = (bf16)((s0.y + s1.y + s2.y + s3.y + bb.y) * scale);
        o[2] = (bf16)((s0.z + s1.z + s2.z + s3.z + bb.z) * scale);
        o[3] = (bf16)((s0.w + s1.w + s2.w + s3.w + bb.w) * scale);
        *(bf16x4*)(&St[row][c4]) = o;
    }
    __syncthreads();
    bf16x8 qf0 = *(const bf16x8*)(&St[lr][lq * 8]);
    bf16x8 qf1 = *(const bf16x8*)(&St[lr][32 + lq * 8]);

    // ---- phase 1a: QK^T, 10 half-chunks of 32 keys; wave w does {w,w+4,w+8}
    const int base = ((q0 - band) >> 6) * 64;         // floor-div chunk base
    #pragma unroll
    for (int i = 0; i < 3; i++) {
        const int h = wave + i * 4;
        if (h < 10) {
            const int kj0 = base + h * 32;
            floatx4 sc[2] = {};
            #pragma unroll
            for (int t2 = 0; t2 < 2; t2++) {
                int kr = kj0 + t2 * 16 + lr;
                int krc = min(max(kr, 0), S - 1);     // clamp; masked below
                const bf16* kp = kvp + ((size_t)b * S + krc) * 64;
                bf16x8 b0 = *(const bf16x8*)(kp + lq * 8);
                bf16x8 b1 = *(const bf16x8*)(kp + 32 + lq * 8);
                sc[t2] = MFMA(qf0, b0, sc[t2]);
                sc[t2] = MFMA(qf1, b1, sc[t2]);
            }
            #pragma unroll
            for (int t2 = 0; t2 < 2; t2++) {
                int kj = kj0 + t2 * 16 + lr;
                bool kv_ok = (kj >= 0) && (kj < S);
                #pragma unroll
                for (int r = 0; r < 4; r++) {
                    int qi = q0 + lq * 4 + r;
                    int dlt = qi - kj; dlt = dlt < 0 ? -dlt : dlt;
                    float vv = (kv_ok && dlt <= band) ? sc[t2][r] : 0.f;
                    Ss[lq * 4 + r][h * 32 + t2 * 16 + lr] = (bf16)vv;
                }
            }
        }
    }
    __syncthreads();

    // ---- phase 1b: PV, d-tile = wave, all 320 keys; acc in 4 VGPRs ----
    {
        floatx4 acc = {};
        const bf16* vrow = kvT + ((size_t)b * 64 + wave * 16 + lr) * S;
        #pragma unroll
        for (int h = 0; h < 10; h++) {
            bf16x8 sa = *(const bf16x8*)(&Ss[lr][h * 32 + lq * 8]);
            int kb = base + h * 32 + lq * 8;          // 8-aligned segment
            int kbc = min(max(kb, 0), S - 8);         // clamp; Ss entries are 0
            bf16x8 vb = *(const bf16x8*)(vrow + kbc);
            acc = MFMA(sa, vb, acc);
        }
        // own St columns [wave*16, wave*16+16): no cross-wave reduce
        #pragma unroll
        for (int r = 0; r < 4; r++)
            St[lq * 4 + r][wave * 16 + lr] = (bf16)acc[r];
    }
    __syncthreads();

    // ---- phase 3: swapped-operand epilogue, float4 stores ----
    bf16x8 af0 = *(const bf16x8*)(&St[lr][lq * 8]);   // B-frag: att[q=lr][k]
    bf16x8 af1 = *(const bf16x8*)(&St[lr][32 + lq * 8]);
    float* orow = out + ((size_t)b * S + q0) * 512;
    #pragma unroll
    for (int i = 0; i < 8; i++) {
        const int tp = wave * 8 + i;
        const bf16* wp = WoT + (size_t)(tp * 16 + lr) * 64;
        bf16x8 w0 = *(const bf16x8*)(wp + lq * 8);    // A-frag: Wo^T[col][k]
        bf16x8 w1 = *(const bf16x8*)(wp + 32 + lq * 8);
        floatx4 o = {};
        o = MFMA(w0, af0, o);                         // D[m=out_col][n=q]
        o = MFMA(w1, af1, o);
        float4 bb = *(const float4*)(bo + tp * 16 + lq * 4);
        float4 ov;
        ov.x = o[0] + bb.x; ov.y = o[1] + bb.y;
        ov.z = o[2] + bb.z; ov.w = o[3] + bb.w;
        *(float4*)(orow + (size_t)lr * 512 + tp * 16 + lq * 4) = ov;
    }
}

extern "C" void kernel_launch(void* const* d_in, const int* in_sizes, int n_in,
                              void* d_out, int out_size, void* d_ws, size_t ws_size,
                              hipStream_t stream) {
    const float* query = (const float*)d_in[0];
    const float* value = (const float*)d_in[1];
    const float* Wi    = (const float*)d_in[2];
    const float* bi    = (const float*)d_in[3];
    const float* Wo    = (const float*)d_in[4];
    const float* bo    = (const float*)d_in[5];
    const int*   band  = (const int*)d_in[6];
    float* out = (float*)d_out;

    const int Dk = in_sizes[3];            // 64
    const int D  = in_sizes[5];            // 512
    const int S  = 4096;                   // fixed by the benchmark
    const int BS = in_sizes[0] / D;        // 16384
    const int B  = BS / S;                 // 4
    const float scale = 1.0f / sqrtf((float)Dk);

    bf16* WiT = (bf16*)d_ws;
    bf16* WoT = WiT + 32768;
    bf16* kvp = WoT + 32768;
    bf16* kvT = kvp + (size_t)BS * 64;

    prep_weights<<<16, 256, 0, stream>>>(Wi, Wo, WiT, WoT);

    proj_in_kernel<<<dim3(BS / 16), 256, 0, stream>>>(
        value, WiT, bi, kvp, kvT, D, S);

    band_attn_out_kernel<<<dim3(BS / 16), 256, 0, stream>>>(
        query, WiT, bi, kvp, kvT, band, WoT, bo, out, D, S, scale);
}

// Round 2
// 145.094 us; speedup vs baseline: 1.0256x; 1.0256x over previous
//
#include <hip/hip_runtime.h>
#include <math.h>

// ---------------------------------------------------------------------------
// SelectiveAttention, bf16-MFMA, 3-kernel pipeline.
// R11: band_attn_out restructured as BARRIER-FREE PER-WAVE pipeline.
//   R10 counters: band_attn = 43 us with MfmaUtil 2.8%, VALUBusy 6.3%,
//   HBM 20%, occupancy 31% -> pure latency/serialization bound. Grid ==
//   resident set, so kernel time == per-block critical path, and the 5
//   barrier-fenced phases force all waves to stall together on L2-latency
//   kv/weight loads.
//   Fix: one 16-q strip per WAVE, 64-thread blocks, grid 1024. Each wave:
//     q-proj (full K=512, 64 MFMAs, no cross-wave K-split/reduce)
//     -> QK^T (10 half-chunks) -> mask -> PV (4 d-tiles) -> @Wo epilogue.
//   Zero __syncthreads; LDS only for same-wave layout transposes (in-order
//   write->read, the R9-proven pattern). Full unroll = one long stream the
//   compiler can software-pipeline end-to-end.
//   + wave-uniform fast path skips band-mask VALU for interior chunks.
//   + swapped-operand float4 epilogue (correctness-proven in R10).
// prep_weights / proj_in are IDENTICAL to R9/R10 (measured-best, untouched).
//
// B=4, S=4096, D=512, Dk=64, band=128.
//
// MFMA 16x16x32 bf16 layouts (m89-verified):
//   A-frag: lane l holds A[m=l&15][k=(l>>4)*8+j]  (16B contiguous)
//   B-frag: lane l holds B[k=(l>>4)*8+j][n=l&15]  (B^T storage -> 16B reads)
//   C/D:    lane l, reg r -> C[row=(l>>4)*4+r][col=l&15]
// ---------------------------------------------------------------------------

typedef __bf16 bf16;
using bf16x4  = __attribute__((ext_vector_type(4))) __bf16;
using bf16x8  = __attribute__((ext_vector_type(8))) __bf16;
using floatx4 = __attribute__((ext_vector_type(4))) float;

#define MFMA(a, b, c) __builtin_amdgcn_mfma_f32_16x16x32_bf16(a, b, c, 0, 0, 0)

// WiT[n][k]=Wi[k][n] (64x512 bf16), WoT[n][k]=Wo[k][n] (512x64 bf16).
__global__ __launch_bounds__(256) void prep_weights(
    const float* __restrict__ Wi, const float* __restrict__ Wo,
    bf16* __restrict__ WiT, bf16* __restrict__ WoT)
{
    __shared__ float T[64][65];
    const int blk = blockIdx.x, tid = threadIdx.x;
    if (blk < 8) {
        const int k0 = blk * 64;
        #pragma unroll
        for (int i = 0; i < 4; i++) {
            int idx4 = tid * 4 + i;
            int r = idx4 >> 4, c4 = (idx4 & 15) * 4;
            float4 f = *(const float4*)(Wi + (size_t)(k0 + r) * 64 + c4);
            T[r][c4 + 0] = f.x; T[r][c4 + 1] = f.y;
            T[r][c4 + 2] = f.z; T[r][c4 + 3] = f.w;
        }
        __syncthreads();
        #pragma unroll
        for (int i = 0; i < 2; i++) {
            int seg = tid * 2 + i;
            int n = seg >> 3, k8 = (seg & 7) * 8;
            bf16x8 v;
            #pragma unroll
            for (int j = 0; j < 8; j++) v[j] = (bf16)T[k8 + j][n];
            *(bf16x8*)(WiT + (size_t)n * 512 + k0 + k8) = v;
        }
    } else {
        const int n0 = (blk - 8) * 64;
        #pragma unroll
        for (int i = 0; i < 4; i++) {
            int idx4 = tid * 4 + i;
            int r = idx4 >> 4, c4 = (idx4 & 15) * 4;
            float4 f = *(const float4*)(Wo + (size_t)r * 512 + n0 + c4);
            T[r][c4 + 0] = f.x; T[r][c4 + 1] = f.y;
            T[r][c4 + 2] = f.z; T[r][c4 + 3] = f.w;
        }
        __syncthreads();
        #pragma unroll
        for (int i = 0; i < 2; i++) {
            int seg = tid * 2 + i;
            int n = seg >> 3, k8 = (seg & 7) * 8;
            bf16x8 v;
            #pragma unroll
            for (int j = 0; j < 8; j++) v[j] = (bf16)T[k8 + j][n];
            *(bf16x8*)(WoT + (size_t)(n0 + n) * 64 + k8) = v;
        }
    }
}

// One block = 16 rows of value. Wave w covers k in [w*128,(w+1)*128). LDS
// reduce -> kvp row-major + kvT[d][s] transposed.  (UNCHANGED from R9.)
__global__ __launch_bounds__(256, 4) void proj_in_kernel(
    const float* __restrict__ v, const bf16* __restrict__ WiT,
    const float* __restrict__ bi, bf16* __restrict__ kvp,
    bf16* __restrict__ kvT, int K, int S)
{
    __shared__ float P[4][16][68];                    // [wave][row][col]
    const int tid = threadIdx.x;
    const int wave = tid >> 6, lane = tid & 63;
    const int lr = lane & 15, lq = lane >> 4;
    const int row0 = blockIdx.x * 16;
    const float* xrow = v + (size_t)(row0 + lr) * K + wave * 128;
    const bf16* wrow = WiT + wave * 128;

    floatx4 acc[4] = {};
    #pragma unroll
    for (int ks = 0; ks < 4; ks++) {
        const int k0 = ks * 32 + lq * 8;
        float4 a0 = *(const float4*)(xrow + k0);
        float4 a1 = *(const float4*)(xrow + k0 + 4);
        bf16x8 af;
        af[0] = (bf16)a0.x; af[1] = (bf16)a0.y; af[2] = (bf16)a0.z; af[3] = (bf16)a0.w;
        af[4] = (bf16)a1.x; af[5] = (bf16)a1.y; af[6] = (bf16)a1.z; af[7] = (bf16)a1.w;
        #pragma unroll
        for (int t = 0; t < 4; t++) {
            bf16x8 bfv = *(const bf16x8*)(wrow + (size_t)(t * 16 + lr) * K + k0);
            acc[t] = MFMA(af, bfv, acc[t]);
        }
    }
    #pragma unroll
    for (int t = 0; t < 4; t++)
        #pragma unroll
        for (int r = 0; r < 4; r++)
            P[wave][lq * 4 + r][t * 16 + lr] = acc[t][r];
    __syncthreads();

    {   // reduce + row-major write
        const int row = tid >> 4, c4 = (tid & 15) * 4;
        float4 s0 = *(const float4*)&P[0][row][c4];
        float4 s1 = *(const float4*)&P[1][row][c4];
        float4 s2 = *(const float4*)&P[2][row][c4];
        float4 s3 = *(const float4*)&P[3][row][c4];
        float4 bb = *(const float4*)(bi + c4);
        bf16x4 o;
        o[0] = (bf16)(s0.x + s1.x + s2.x + s3.x + bb.x);
        o[1] = (bf16)(s0.y + s1.y + s2.y + s3.y + bb.y);
        o[2] = (bf16)(s0.z + s1.z + s2.z + s3.z + bb.z);
        o[3] = (bf16)(s0.w + s1.w + s2.w + s3.w + bb.w);
        *(bf16x4*)(kvp + (size_t)(row0 + row) * 64 + c4) = o;
    }
    {   // kvT[d][s] transpose write
        const int d = tid >> 2, s4 = (tid & 3) * 4;
        const int b = row0 >> 12, s0r = row0 & (S - 1);
        const float bb = bi[d];
        bf16x4 o;
        #pragma unroll
        for (int i = 0; i < 4; i++) {
            float s = P[0][s4 + i][d] + P[1][s4 + i][d]
                    + P[2][s4 + i][d] + P[3][s4 + i][d] + bb;
            o[i] = (bf16)s;
        }
        *(bf16x4*)(kvT + ((size_t)b * 64 + d) * S + s0r + s4) = o;
    }
}

// One 64-thread block = one wave = one 16-query strip, fully independent.
// No __syncthreads anywhere. LDS used only for same-wave C-layout -> A-frag
// transposes (in-order per wave; compiler inserts lgkmcnt).
__global__ __launch_bounds__(64, 2) void band_attn_out_kernel(
    const float* __restrict__ query, const bf16* __restrict__ WiT,
    const float* __restrict__ bi, const bf16* __restrict__ kvp,
    const bf16* __restrict__ kvT, const int* __restrict__ band_ptr,
    const bf16* __restrict__ WoT, const float* __restrict__ bo,
    float* __restrict__ out, int K, int S, float scale)
{
    __shared__ bf16 Qs[16][80];                       // q strip, reused as att
    __shared__ bf16 Ss[16][336];                      // 320-key score strip
    const int lane = threadIdx.x;                     // 0..63
    const int lr = lane & 15, lq = lane >> 4;
    const int gs = blockIdx.x;                        // strip id
    const int b = gs >> 8;                            // 256 strips per batch
    const int q0 = (gs & 255) * 16;
    const int band = band_ptr[0];

    // ---- q-proj: full K=512, 4 n-tiles, 16 k-steps, this wave only ----
    {
        const float* xrow = query + ((size_t)b * S + q0 + lr) * K;
        floatx4 qa[4] = {};
        #pragma unroll
        for (int ks = 0; ks < 16; ks++) {
            const int k0 = ks * 32 + lq * 8;
            float4 a0 = *(const float4*)(xrow + k0);
            float4 a1 = *(const float4*)(xrow + k0 + 4);
            bf16x8 af;
            af[0] = (bf16)a0.x; af[1] = (bf16)a0.y; af[2] = (bf16)a0.z; af[3] = (bf16)a0.w;
            af[4] = (bf16)a1.x; af[5] = (bf16)a1.y; af[6] = (bf16)a1.z; af[7] = (bf16)a1.w;
            #pragma unroll
            for (int t = 0; t < 4; t++) {
                bf16x8 bfv = *(const bf16x8*)(WiT + (size_t)(t * 16 + lr) * K + k0);
                qa[t] = MFMA(af, bfv, qa[t]);
            }
        }
        // C-layout -> LDS with bias+scale (lane holds rows lq*4+r, col t*16+lr)
        #pragma unroll
        for (int t = 0; t < 4; t++) {
            float bb = bi[t * 16 + lr];
            #pragma unroll
            for (int r = 0; r < 4; r++)
                Qs[lq * 4 + r][t * 16 + lr] = (bf16)((qa[t][r] + bb) * scale);
        }
    }
    // A-frag read-back (same wave, in-order)
    bf16x8 qf0 = *(const bf16x8*)(&Qs[lr][lq * 8]);
    bf16x8 qf1 = *(const bf16x8*)(&Qs[lr][32 + lq * 8]);

    // ---- QK^T: 10 half-chunks of 32 keys, all by this wave ----
    const int base = ((q0 - band) >> 6) * 64;         // floor-div chunk base
    #pragma unroll
    for (int h = 0; h < 10; h++) {
        const int kj0 = base + h * 32;
        floatx4 sc[2] = {};
        #pragma unroll
        for (int t2 = 0; t2 < 2; t2++) {
            int kr = kj0 + t2 * 16 + lr;
            int krc = min(max(kr, 0), S - 1);         // clamp; masked below
            const bf16* kp = kvp + ((size_t)b * S + krc) * 64;
            bf16x8 b0 = *(const bf16x8*)(kp + lq * 8);
            bf16x8 b1 = *(const bf16x8*)(kp + 32 + lq * 8);
            sc[t2] = MFMA(qf0, b0, sc[t2]);
            sc[t2] = MFMA(qf1, b1, sc[t2]);
        }
        // wave-uniform: is this chunk fully in-band and in-range for all 16 q?
        const int lo = kj0, hi = kj0 + 31;
        const bool full = (lo >= 0) && (hi < S) &&
                          (lo >= q0 + 15 - band) && (hi <= q0 + band);
        if (full) {
            #pragma unroll
            for (int t2 = 0; t2 < 2; t2++)
                #pragma unroll
                for (int r = 0; r < 4; r++)
                    Ss[lq * 4 + r][h * 32 + t2 * 16 + lr] = (bf16)sc[t2][r];
        } else {
            #pragma unroll
            for (int t2 = 0; t2 < 2; t2++) {
                int kj = kj0 + t2 * 16 + lr;
                bool kv_ok = (kj >= 0) && (kj < S);
                #pragma unroll
                for (int r = 0; r < 4; r++) {
                    int qi = q0 + lq * 4 + r;
                    int dlt = qi - kj; dlt = dlt < 0 ? -dlt : dlt;
                    float vv = (kv_ok && dlt <= band) ? sc[t2][r] : 0.f;
                    Ss[lq * 4 + r][h * 32 + t2 * 16 + lr] = (bf16)vv;
                }
            }
        }
    }

    // ---- PV: all 320 keys, 4 d-tiles, acc in 16 VGPRs ----
    floatx4 acc[4] = {};
    #pragma unroll
    for (int h = 0; h < 10; h++) {
        bf16x8 sa = *(const bf16x8*)(&Ss[lr][h * 32 + lq * 8]);
        int kb = base + h * 32 + lq * 8;              // 8-aligned segment
        int kbc = min(max(kb, 0), S - 8);             // clamp; Ss entries are 0
        #pragma unroll
        for (int t = 0; t < 4; t++) {
            bf16x8 vb = *(const bf16x8*)(kvT + ((size_t)b * 64 + t * 16 + lr) * S + kbc);
            acc[t] = MFMA(sa, vb, acc[t]);
        }
    }
    // att strip -> LDS (reuse Qs; q frags already consumed)
    #pragma unroll
    for (int t = 0; t < 4; t++)
        #pragma unroll
        for (int r = 0; r < 4; r++)
            Qs[lq * 4 + r][t * 16 + lr] = (bf16)acc[t][r];
    bf16x8 af0 = *(const bf16x8*)(&Qs[lr][lq * 8]);
    bf16x8 af1 = *(const bf16x8*)(&Qs[lr][32 + lq * 8]);

    // ---- epilogue: swapped operands, D[m=out_col][n=q], float4 stores ----
    float* orow = out + ((size_t)b * S + q0) * 512;
    #pragma unroll
    for (int tp = 0; tp < 32; tp++) {
        const bf16* wp = WoT + (size_t)(tp * 16 + lr) * 64;
        bf16x8 w0 = *(const bf16x8*)(wp + lq * 8);    // A-frag: Wo^T[col][k]
        bf16x8 w1 = *(const bf16x8*)(wp + 32 + lq * 8);
        floatx4 o = {};
        o = MFMA(w0, af0, o);                         // D[m=out_col][n=q]
        o = MFMA(w1, af1, o);
        float4 bb = *(const float4*)(bo + tp * 16 + lq * 4);
        float4 ov;
        ov.x = o[0] + bb.x; ov.y = o[1] + bb.y;
        ov.z = o[2] + bb.z; ov.w = o[3] + bb.w;
        *(float4*)(orow + (size_t)lr * 512 + tp * 16 + lq * 4) = ov;
    }
}

extern "C" void kernel_launch(void* const* d_in, const int* in_sizes, int n_in,
                              void* d_out, int out_size, void* d_ws, size_t ws_size,
                              hipStream_t stream) {
    const float* query = (const float*)d_in[0];
    const float* value = (const float*)d_in[1];
    const float* Wi    = (const float*)d_in[2];
    const float* bi    = (const float*)d_in[3];
    const float* Wo    = (const float*)d_in[4];
    const float* bo    = (const float*)d_in[5];
    const int*   band  = (const int*)d_in[6];
    float* out = (float*)d_out;

    const int Dk = in_sizes[3];            // 64
    const int D  = in_sizes[5];            // 512
    const int S  = 4096;                   // fixed by the benchmark
    const int BS = in_sizes[0] / D;        // 16384
    const int B  = BS / S;                 // 4
    const float scale = 1.0f / sqrtf((float)Dk);

    bf16* WiT = (bf16*)d_ws;
    bf16* WoT = WiT + 32768;
    bf16* kvp = WoT + 32768;
    bf16* kvT = kvp + (size_t)BS * 64;

    prep_weights<<<16, 256, 0, stream>>>(Wi, Wo, WiT, WoT);

    proj_in_kernel<<<dim3(BS / 16), 256, 0, stream>>>(
        value, WiT, bi, kvp, kvT, D, S);

    band_attn_out_kernel<<<dim3(BS / 16), 64, 0, stream>>>(
        query, WiT, bi, kvp, kvT, band, WoT, bo, out, D, S, scale);
}